// Round 7
// baseline (99.356 us; speedup 1.0000x reference)
//
#include <hip/hip_runtime.h>
#include <hip/hip_bf16.h>
#include <stdint.h>

#define NB 8192
#define DK 256
// gamma * log2(e): epilogue uses native exp2
#define GSCALE 14.426950408889634f

typedef short short8 __attribute__((ext_vector_type(8)));
typedef float f32x4 __attribute__((ext_vector_type(4)));

__device__ __forceinline__ unsigned short f32_to_bf16(float f) {
  uint32_t u = __builtin_bit_cast(uint32_t, f);
  u += 0x7FFFu + ((u >> 16) & 1u);   // RNE
  return (unsigned short)(u >> 16);
}

// One wave per row: 1/max(||row||,eps); gamma*log2e folded into e side; store bf16.
__global__ __launch_bounds__(256) void norm_kernel(const float* __restrict__ e,
                                                   const float* __restrict__ v,
                                                   unsigned short* __restrict__ ebf,
                                                   unsigned short* __restrict__ vbf) {
  int wave = threadIdx.x >> 6;
  int lane = threadIdx.x & 63;
  int row = blockIdx.x * 4 + wave;
  const float* src;
  unsigned short* dst;
  float mul;
  if (row < NB) {
    src = e + (size_t)row * DK; dst = ebf + (size_t)row * DK; mul = GSCALE;
  } else {
    src = v + (size_t)(row - NB) * DK; dst = vbf + (size_t)(row - NB) * DK; mul = 1.0f;
  }
  float4 x = reinterpret_cast<const float4*>(src)[lane];
  float ss = x.x * x.x + x.y * x.y + x.z * x.z + x.w * x.w;
  #pragma unroll
  for (int off = 32; off >= 1; off >>= 1) ss += __shfl_xor(ss, off);
  float s = mul / fmaxf(sqrtf(ss), 1e-8f);
  ushort4 o;
  o.x = f32_to_bf16(x.x * s);
  o.y = f32_to_bf16(x.y * s);
  o.z = f32_to_bf16(x.z * s);
  o.w = f32_to_bf16(x.w * s);
  reinterpret_cast<ushort4*>(dst)[lane] = o;
}

// 512 blocks x 4 waves (2 blocks/CU -> two independent barrier domains).
// Block: 64 e-rows x 2048 v-cols. Wave w: 64 rows x cols [w*64, w*64+64) of
// each 256-col j-tile. A panel (64 rows x 256 k) pinned in registers via
// opaque asm (prevents the compiler from sinking the loop-invariant A loads
// back into the K-loop -- the R4-R6 regression: VGPR capped at 128 + ~21 MB
// of scratch WRITE_SIZE). B double-buffered in LDS, counted-vmcnt pipeline.
__global__ __launch_bounds__(256) void score_kernel(const unsigned short* __restrict__ ebf,
                                                    const unsigned short* __restrict__ vbf,
                                                    float* __restrict__ out) {
  __shared__ unsigned short smem[2][16384];   // 2 x 32 KiB B double-buffer
  __shared__ float colsum[2048];              // 8 KiB
  __shared__ float rowsum[4][64];             // 1 KiB

  const int tid = threadIdx.x;
  const int w = tid >> 6;          // 0..3 == wc
  const int lane = tid & 63;
  const int lo16 = lane & 15;
  const int q4 = lane >> 4;        // 0..3

  // 512 blocks round-robin over 8 XCDs: id&3 == (XCD&3) -> each XCD touches
  // exactly one jc chunk of B (1 MiB, L2-resident) + 64 A panels (2 MiB).
  int id = blockIdx.x;
  int jc = id & 3;                  // 0..3   (column chunk of 2048)
  int bi = id >> 2;                 // 0..127 (row panel of 64)

  // ---- A panel -> registers: row = bi*64 + m*16 + lo16, A[m][s] holds
  //      k = s*32 + q4*8 .. +8. Pinned with opaque asm. ----
  const char* eBase = (const char*)ebf;
  short8 A[4][8];
  #pragma unroll
  for (int m = 0; m < 4; ++m) {
    const char* rp = eBase + (size_t)(bi * 64 + m * 16 + lo16) * 512 + q4 * 16;
    #pragma unroll
    for (int s = 0; s < 8; ++s) {
      A[m][s] = *(const short8*)(rp + s * 64);
      asm volatile("" : "+v"(A[m][s]));   // opaque producer: no remat/sink
    }
  }

  const char* vC = (const char*)vbf + (size_t)(jc * 2048) * 512;

  // Stage chunk c (j = c>>2, kt = c&3) into smem[c&1], swizzled (rule 21).
  auto stageB = [&](int c) {
    int buf = c & 1;
    const char* vP = vC + (size_t)(c >> 2) * 256 * 512;
    int ktoff = (c & 3) * 128;
    #pragma unroll
    for (int u = 0; u < 8; ++u) {
      int p = ((w * 8 + u) * 64 + lane) * 16;       // linear byte in 32 KiB chunk
      int r = p >> 7;                                // v-row (128 B rows)
      int lc = (p & 127) ^ ((r & 7) << 4);           // inverse-swizzled col
      size_t goff = (size_t)r * 512 + ktoff + lc;
      unsigned short* dst = &smem[buf][(w * 8 + u) * 512];
      __builtin_amdgcn_global_load_lds((const __attribute__((address_space(1))) uint32_t*)(vP + goff),
                                       (__attribute__((address_space(3))) uint32_t*)dst, 16, 0, 0);
    }
  };

  f32x4 acc[4][4];
  #pragma unroll
  for (int m = 0; m < 4; ++m)
    #pragma unroll
    for (int n = 0; n < 4; ++n)
      #pragma unroll
      for (int q = 0; q < 4; ++q)
        acc[m][n][q] = 0.0f;

  float rowAcc[4][4];
  #pragma unroll
  for (int m = 0; m < 4; ++m)
    #pragma unroll
    for (int g = 0; g < 4; ++g)
      rowAcc[m][g] = 0.0f;

  stageB(0);

  for (int j8 = 0; j8 < 8; ++j8) {
    #pragma unroll
    for (int kt = 0; kt < 4; ++kt) {
      const int c = j8 * 4 + kt;
      stageB((c + 1) & 31);                          // prefetch stays in flight
      asm volatile("s_waitcnt vmcnt(8)" ::: "memory");   // chunk c done, c+1 pending
      __builtin_amdgcn_s_barrier();
      asm volatile("" ::: "memory");
      const char* LB = (const char*)&smem[kt & 1][0];
      short8 bfr[2][4];
      #pragma unroll
      for (int ks = 0; ks < 2; ++ks)
        #pragma unroll
        for (int n = 0; n < 4; ++n) {
          int row = w * 64 + n * 16 + lo16;
          int byte = row * 128 + ((ks * 64 + q4 * 16) ^ ((row & 7) << 4));
          bfr[ks][n] = *(const short8*)(LB + byte);
        }
      asm volatile("s_waitcnt lgkmcnt(0)" ::: "memory");
      __builtin_amdgcn_sched_barrier(0);             // rule #18
      __builtin_amdgcn_s_setprio(1);
      #pragma unroll
      for (int ks = 0; ks < 2; ++ks)
        #pragma unroll
        for (int m = 0; m < 4; ++m)
          #pragma unroll
          for (int n = 0; n < 4; ++n)
            acc[m][n] = __builtin_amdgcn_mfma_f32_16x16x32_bf16(A[m][kt * 2 + ks], bfr[ks][n], acc[m][n], 0, 0, 0);
      __builtin_amdgcn_s_setprio(0);

      if (kt == 3) {
        // per-j epilogue: E = exp2(acc); rows -> regs, cols -> LDS (lgkm
        // domain, never pollutes the vmcnt queue).
        // C/D layout: col = lane&15 (B side), row = (lane>>4)*4 + reg (A side).
        int localbase = j8 * 256 + w * 64;
        float colpart[4] = {0.f, 0.f, 0.f, 0.f};
        #pragma unroll
        for (int m = 0; m < 4; ++m)
          #pragma unroll
          for (int n = 0; n < 4; ++n)
            #pragma unroll
            for (int g = 0; g < 4; ++g) {
              float ev = __builtin_amdgcn_exp2f(acc[m][n][g]);
              rowAcc[m][g] += ev;
              colpart[n] += ev;
              acc[m][n][g] = 0.0f;
            }
        #pragma unroll
        for (int n = 0; n < 4; ++n) {
          float cs = colpart[n];
          cs += __shfl_xor(cs, 16);
          cs += __shfl_xor(cs, 32);
          if (q4 == n) {
            colsum[localbase + n * 16 + lo16] = cs;
          }
        }
      }
      __builtin_amdgcn_s_barrier();                  // slot-reuse protection
      asm volatile("" ::: "memory");
    }
  }

  // ---- rows: reduce 16 cols within q4-group; lane with lo16==m*4+g holds
  //      row m*16 + q4*4 + g; stage per-wave to LDS, merge 4 waves ----
  #pragma unroll
  for (int m = 0; m < 4; ++m)
    #pragma unroll
    for (int g = 0; g < 4; ++g) {
      float rs = rowAcc[m][g];
      rs += __shfl_xor(rs, 1);
      rs += __shfl_xor(rs, 2);
      rs += __shfl_xor(rs, 4);
      rs += __shfl_xor(rs, 8);
      if (lo16 == m * 4 + g) {
        rowsum[w][m * 16 + q4 * 4 + g] = rs;
      }
    }

  __syncthreads();   // drains wraparound prefetch + all LDS writes

  // ---- tail: all global atomics in one dependent-free burst ----
  #pragma unroll
  for (int k = 0; k < 8; ++k) {
    int c = tid + k * 256;
    atomicAdd(&out[NB + jc * 2048 + c], colsum[c]);
  }
  if (tid < 64) {
    float s = rowsum[0][tid] + rowsum[1][tid] + rowsum[2][tid] + rowsum[3][tid];
    atomicAdd(&out[bi * 64 + tid], s);
  }
}

extern "C" void kernel_launch(void* const* d_in, const int* in_sizes, int n_in,
                              void* d_out, int out_size, void* d_ws, size_t ws_size,
                              hipStream_t stream) {
  const float* e = (const float*)d_in[0];
  const float* v = (const float*)d_in[1];
  float* out = (float*)d_out;
  unsigned short* ebf = (unsigned short*)d_ws;
  unsigned short* vbf = ebf + (size_t)NB * DK;
  hipMemsetAsync(d_out, 0, (size_t)2 * NB * sizeof(float), stream);
  hipLaunchKernelGGL(norm_kernel, dim3((2 * NB) / 4), dim3(256), 0, stream, e, v, ebf, vbf);
  hipLaunchKernelGGL(score_kernel, dim3(512), dim3(256), 0, stream, ebf, vbf, out);
}

// Round 8
// 98.669 us; speedup vs baseline: 1.0070x; 1.0070x over previous
//
#include <hip/hip_runtime.h>
#include <hip/hip_bf16.h>
#include <stdint.h>

#define NB 8192
#define DK 256
// gamma * log2(e): epilogue uses native exp2
#define GSCALE 14.426950408889634f

typedef short short8 __attribute__((ext_vector_type(8)));
typedef float f32x4 __attribute__((ext_vector_type(4)));

__device__ __forceinline__ unsigned short f32_to_bf16(float f) {
  uint32_t u = __builtin_bit_cast(uint32_t, f);
  u += 0x7FFFu + ((u >> 16) & 1u);   // RNE
  return (unsigned short)(u >> 16);
}

// One wave per row: 1/max(||row||,eps); gamma*log2e folded into e side; store bf16.
__global__ __launch_bounds__(256) void norm_kernel(const float* __restrict__ e,
                                                   const float* __restrict__ v,
                                                   unsigned short* __restrict__ ebf,
                                                   unsigned short* __restrict__ vbf) {
  int wave = threadIdx.x >> 6;
  int lane = threadIdx.x & 63;
  int row = blockIdx.x * 4 + wave;
  const float* src;
  unsigned short* dst;
  float mul;
  if (row < NB) {
    src = e + (size_t)row * DK; dst = ebf + (size_t)row * DK; mul = GSCALE;
  } else {
    src = v + (size_t)(row - NB) * DK; dst = vbf + (size_t)(row - NB) * DK; mul = 1.0f;
  }
  float4 x = reinterpret_cast<const float4*>(src)[lane];
  float ss = x.x * x.x + x.y * x.y + x.z * x.z + x.w * x.w;
  #pragma unroll
  for (int off = 32; off >= 1; off >>= 1) ss += __shfl_xor(ss, off);
  float s = mul / fmaxf(sqrtf(ss), 1e-8f);
  ushort4 o;
  o.x = f32_to_bf16(x.x * s);
  o.y = f32_to_bf16(x.y * s);
  o.z = f32_to_bf16(x.z * s);
  o.w = f32_to_bf16(x.w * s);
  reinterpret_cast<ushort4*>(dst)[lane] = o;
}

// BARRIER-FREE main loop. Every LDS-staged variant (R3-R7) pinned at
// MfmaUtil 14-16%: <=8 lockstep waves/CU convoy on the staging barriers.
// Here: A (64 rows x 256 k) pinned in registers (R7-proven asm pin), B
// fragments loaded per-wave straight from L2-resident vbf through a static
// 4-slot register ring with lookahead 3 (~768 cyc, covers L2 latency).
// Waves are fully independent -- desync replaces barriers. Cols accumulate
// in LDS (lgkm domain; vmcnt queue stays pure B-loads), rows in registers;
// all global atomics in a tail burst.
// Wave = 64 rows x 256 cols (8 j-tiles x 32 cols). 1024 blocks x 4 waves.
__global__ __launch_bounds__(256, 2) void score_kernel(const unsigned short* __restrict__ ebf,
                                                       const unsigned short* __restrict__ vbf,
                                                       float* __restrict__ out) {
  __shared__ float colsum[256];

  const int tid = threadIdx.x;
  const int w = tid >> 6;          // 0..3 (row sub-panel)
  const int lane = tid & 63;
  const int lo16 = lane & 15;
  const int q4 = lane >> 4;        // 0..3

  // 1024 blocks: xcd = id&7 (dispatch round-robin), 4 col-strips per XCD
  // -> per-XCD B working set = 4 x 128 KiB = 512 KiB, L2-resident.
  int id = blockIdx.x;
  int xcd = id & 7;
  int t = id >> 3;                  // 0..127
  int strip = (xcd << 2) | (t & 3); // 0..31 (256-col strip)
  int rowblk = t >> 2;              // 0..31 (256-row block)

  colsum[tid] = 0.0f;
  __syncthreads();

  const int rowpanel = rowblk * 256 + w * 64;

  // ---- A panel -> registers, pinned: row = rowpanel + m*16 + lo16,
  //      A[m][s] holds k = s*32 + q4*8 .. +8 ----
  const char* eBase = (const char*)ebf;
  short8 A[4][8];
  #pragma unroll
  for (int m = 0; m < 4; ++m) {
    const char* rp = eBase + (size_t)(rowpanel + m * 16 + lo16) * 512 + q4 * 16;
    #pragma unroll
    for (int s = 0; s < 8; ++s) {
      A[m][s] = *(const short8*)(rp + s * 64);
      asm volatile("" : "+v"(A[m][s]));   // opaque producer: no remat/sink
    }
  }

  // ---- B per-lane pointers (n = 0,1): col = strip*256 + j*32 + n*16 + lo16,
  //      byte = col*512 + ks*64 + q4*16; j advances by 16384 B ----
  const char* p0 = (const char*)vbf + (size_t)(strip * 256 + lo16) * 512 + q4 * 16;
  const char* p1 = (const char*)vbf + (size_t)(strip * 256 + 16 + lo16) * 512 + q4 * 16;

  f32x4 acc[4][2];
  #pragma unroll
  for (int m = 0; m < 4; ++m)
    #pragma unroll
    for (int n = 0; n < 2; ++n)
      #pragma unroll
      for (int q = 0; q < 4; ++q)
        acc[m][n][q] = 0.0f;

  float rowAcc[4][4];
  #pragma unroll
  for (int m = 0; m < 4; ++m)
    #pragma unroll
    for (int g = 0; g < 4; ++g)
      rowAcc[m][g] = 0.0f;

#define LD(S, OFF)                                   \
  do {                                               \
    S[0] = *(const short8*)(p0 + (OFF));             \
    S[1] = *(const short8*)(p1 + (OFF));             \
  } while (0)

#define MM(S, KS)                                                                        \
  do {                                                                                   \
    _Pragma("unroll")                                                                    \
    for (int m = 0; m < 4; ++m) {                                                        \
      acc[m][0] = __builtin_amdgcn_mfma_f32_16x16x32_bf16(A[m][KS], S[0], acc[m][0], 0, 0, 0); \
      acc[m][1] = __builtin_amdgcn_mfma_f32_16x16x32_bf16(A[m][KS], S[1], acc[m][1], 0, 0, 0); \
    }                                                                                    \
  } while (0)

  short8 S0[2], S1[2], S2[2], S3[2];
  // prologue: ks0..ks2 of j=0 in flight
  LD(S0, 0);
  LD(S1, 64);
  LD(S2, 128);

  for (int j = 0; j < 8; ++j) {
    LD(S3, 192);  MM(S0, 0);     // ks3 in flight; compute ks0
    LD(S0, 256);  MM(S1, 1);
    LD(S1, 320);  MM(S2, 2);
    LD(S2, 384);  MM(S3, 3);
    LD(S3, 448);  MM(S0, 4);
    // advance to next j-tile (wrap to strip start on last j: valid reads,
    // results unused -- avoids OOB past vbf)
    int bump = (j == 7) ? -(7 * 16384) : 16384;
    p0 += bump; p1 += bump;
    LD(S0, 0);    MM(S1, 5);     // next-j ks0 in flight
    LD(S1, 64);   MM(S2, 6);
    LD(S2, 128);  MM(S3, 7);

    // ---- per-j epilogue (overlaps next-j loads already in flight):
    // E = exp2(acc); rows -> regs, cols -> LDS atomics (lgkm domain).
    // C/D layout: col = lane&15 (B side), row = (lane>>4)*4 + reg (A side).
    float colpart[2] = {0.f, 0.f};
    #pragma unroll
    for (int m = 0; m < 4; ++m)
      #pragma unroll
      for (int n = 0; n < 2; ++n)
        #pragma unroll
        for (int g = 0; g < 4; ++g) {
          float ev = __builtin_amdgcn_exp2f(acc[m][n][g]);
          rowAcc[m][g] += ev;
          colpart[n] += ev;
          acc[m][n][g] = 0.0f;
        }
    #pragma unroll
    for (int n = 0; n < 2; ++n) {
      float cs = colpart[n];
      cs += __shfl_xor(cs, 16);
      cs += __shfl_xor(cs, 32);
      if (q4 == n) {
        atomicAdd(&colsum[j * 32 + n * 16 + lo16], cs);
      }
    }
  }
#undef LD
#undef MM

  // ---- tail: global atomics in one dependent-free burst ----
  __syncthreads();
  atomicAdd(&out[NB + strip * 256 + tid], colsum[tid]);

  #pragma unroll
  for (int m = 0; m < 4; ++m)
    #pragma unroll
    for (int g = 0; g < 4; ++g) {
      float rs = rowAcc[m][g];
      rs += __shfl_xor(rs, 1);
      rs += __shfl_xor(rs, 2);
      rs += __shfl_xor(rs, 4);
      rs += __shfl_xor(rs, 8);
      if (lo16 == m * 4 + g) {
        atomicAdd(&out[rowpanel + m * 16 + q4 * 4 + g], rs);
      }
    }
}

extern "C" void kernel_launch(void* const* d_in, const int* in_sizes, int n_in,
                              void* d_out, int out_size, void* d_ws, size_t ws_size,
                              hipStream_t stream) {
  const float* e = (const float*)d_in[0];
  const float* v = (const float*)d_in[1];
  float* out = (float*)d_out;
  unsigned short* ebf = (unsigned short*)d_ws;
  unsigned short* vbf = ebf + (size_t)NB * DK;
  hipMemsetAsync(d_out, 0, (size_t)2 * NB * sizeof(float), stream);
  hipLaunchKernelGGL(norm_kernel, dim3((2 * NB) / 4), dim3(256), 0, stream, e, v, ebf, vbf);
  hipLaunchKernelGGL(score_kernel, dim3(1024), dim3(256), 0, stream, ebf, vbf, out);
}

// Round 9
// 92.250 us; speedup vs baseline: 1.0770x; 1.0696x over previous
//
#include <hip/hip_runtime.h>
#include <hip/hip_bf16.h>
#include <stdint.h>

#define NB 8192
#define DK 256
// gamma * log2(e): epilogue uses native exp2
#define GSCALE 14.426950408889634f

typedef short short8 __attribute__((ext_vector_type(8)));
typedef float f32x4 __attribute__((ext_vector_type(4)));

__device__ __forceinline__ unsigned short f32_to_bf16(float f) {
  uint32_t u = __builtin_bit_cast(uint32_t, f);
  u += 0x7FFFu + ((u >> 16) & 1u);   // RNE
  return (unsigned short)(u >> 16);
}

// One wave per row: 1/max(||row||,eps); gamma*log2e folded into e side.
// Blocks 0..15 also zero d_out (replaces the hipMemsetAsync launch).
__global__ __launch_bounds__(256) void norm_kernel(const float* __restrict__ e,
                                                   const float* __restrict__ v,
                                                   unsigned short* __restrict__ ebf,
                                                   unsigned short* __restrict__ vbf,
                                                   float* __restrict__ out) {
  if (blockIdx.x < 16) {
    float4 z = {0.f, 0.f, 0.f, 0.f};
    reinterpret_cast<float4*>(out)[blockIdx.x * 256 + threadIdx.x] = z;
  }
  int wave = threadIdx.x >> 6;
  int lane = threadIdx.x & 63;
  int row = blockIdx.x * 4 + wave;
  const float* src;
  unsigned short* dst;
  float mul;
  if (row < NB) {
    src = e + (size_t)row * DK; dst = ebf + (size_t)row * DK; mul = GSCALE;
  } else {
    src = v + (size_t)(row - NB) * DK; dst = vbf + (size_t)(row - NB) * DK; mul = 1.0f;
  }
  float4 x = reinterpret_cast<const float4*>(src)[lane];
  float ss = x.x * x.x + x.y * x.y + x.z * x.z + x.w * x.w;
  #pragma unroll
  for (int off = 32; off >= 1; off >>= 1) ss += __shfl_xor(ss, off);
  float s = mul / fmaxf(sqrtf(ss), 1e-8f);
  ushort4 o;
  o.x = f32_to_bf16(x.x * s);
  o.y = f32_to_bf16(x.y * s);
  o.z = f32_to_bf16(x.z * s);
  o.w = f32_to_bf16(x.w * s);
  reinterpret_cast<ushort4*>(dst)[lane] = o;
}

// TLP-first redesign: 16 waves/CU (<=128 regs via __launch_bounds__(256,4)).
// Block = 64 rows x 128 cols, 4 waves; each wave = 64 rows x 32 cols, ONE
// K=256 pass (acc = 32 regs only). A panel (64x256, 32 KB) shared in LDS,
// staged once with global_load_lds (swizzled both sides, rule 21); ONE
// barrier per block. B per wave: 4-slot static register ring from L2, no
// barriers in the K-loop. While one wave waits (loads / exp2 chain), 3
// sibling waves per SIMD feed the MFMA pipe -- TLP replaces scheduling.
__global__ __launch_bounds__(256, 4) void score_kernel(const unsigned short* __restrict__ ebf,
                                                       const unsigned short* __restrict__ vbf,
                                                       float* __restrict__ out) {
  __shared__ unsigned short As[64 * 256];   // 32 KB A panel (swizzled)
  __shared__ float rowsum[4][64];           // 1 KB

  const int tid = threadIdx.x;
  const int w = tid >> 6;          // 0..3 (col quarter)
  const int lane = tid & 63;
  const int lo16 = lane & 15;
  const int q4 = lane >> 4;        // 0..3

  // 8192 blocks: xcd = id&7 (dispatch round-robin). Per XCD: 8 colblks,
  // consecutive t walk rowblk within one colblk -> B hot-set 64 KB in L2.
  int id = blockIdx.x;
  int xcd = id & 7;
  int t = id >> 3;                      // 0..1023
  int colblk = (xcd << 3) | (t >> 7);   // 0..63  (128-col strip)
  int rowblk = t & 127;                 // 0..127 (64-row panel)

  // ---- B prologue: issue first 3 ring slots before staging A ----
  const char* bBase = (const char*)vbf + (size_t)(colblk * 128 + w * 32) * 512;
  const char* p0 = bBase + lo16 * 512 + q4 * 16;          // n=0 cols
  const char* p1 = bBase + (16 + lo16) * 512 + q4 * 16;   // n=1 cols

  short8 S[4][2];
  #pragma unroll
  for (int s = 0; s < 3; ++s) {
    S[s][0] = *(const short8*)(p0 + s * 64);
    S[s][1] = *(const short8*)(p1 + s * 64);
  }

  // ---- Stage A panel (64 rows x 512 B) into LDS, swizzled (rule 21) ----
  const char* eP = (const char*)ebf + (size_t)rowblk * 64 * 512;
  #pragma unroll
  for (int u = 0; u < 8; ++u) {
    int chunk = w * 8 + u;                     // 0..31 (1 KB chunks)
    int p = (chunk * 64 + lane) * 16;          // linear byte 0..32767
    int r = p >> 9;                            // row (512 B rows)
    const char* src = eP + (p ^ ((r & 7) << 4));   // pre-swizzled source
    unsigned short* dst = &As[chunk * 512];
    __builtin_amdgcn_global_load_lds((const __attribute__((address_space(1))) uint32_t*)src,
                                     (__attribute__((address_space(3))) uint32_t*)dst, 16, 0, 0);
  }
  asm volatile("s_waitcnt vmcnt(0)" ::: "memory");
  __builtin_amdgcn_s_barrier();
  asm volatile("" ::: "memory");

  f32x4 acc[4][2];
  #pragma unroll
  for (int m = 0; m < 4; ++m)
    #pragma unroll
    for (int n = 0; n < 2; ++n)
      #pragma unroll
      for (int q = 0; q < 4; ++q)
        acc[m][n][q] = 0.0f;

  // ---- K loop: 8 steps, no barriers. Ring lookahead 3. ----
  #pragma unroll
  for (int ks = 0; ks < 8; ++ks) {
    if (ks < 5) {                                // prefetch slot ks+3 (static)
      S[(ks + 3) & 3][0] = *(const short8*)(p0 + (ks + 3) * 64);
      S[(ks + 3) & 3][1] = *(const short8*)(p1 + (ks + 3) * 64);
    }
    short8 af[4];
    #pragma unroll
    for (int m = 0; m < 4; ++m) {
      int row = m * 16 + lo16;
      int byte = row * 512 + ((ks * 64 + q4 * 16) ^ ((row & 7) << 4));
      af[m] = *(const short8*)((const char*)As + byte);
    }
    #pragma unroll
    for (int m = 0; m < 4; ++m) {
      acc[m][0] = __builtin_amdgcn_mfma_f32_16x16x32_bf16(af[m], S[ks & 3][0], acc[m][0], 0, 0, 0);
      acc[m][1] = __builtin_amdgcn_mfma_f32_16x16x32_bf16(af[m], S[ks & 3][1], acc[m][1], 0, 0, 0);
    }
  }

  // ---- one-shot epilogue: E = exp2(acc); rows -> LDS merge, cols -> atomics.
  // C/D layout: col = lane&15 (B side), row = (lane>>4)*4 + reg (A side).
  float colpart[2] = {0.f, 0.f};
  float rp[4][4];
  #pragma unroll
  for (int m = 0; m < 4; ++m)
    #pragma unroll
    for (int g = 0; g < 4; ++g)
      rp[m][g] = 0.0f;

  #pragma unroll
  for (int m = 0; m < 4; ++m)
    #pragma unroll
    for (int n = 0; n < 2; ++n)
      #pragma unroll
      for (int g = 0; g < 4; ++g) {
        float ev = __builtin_amdgcn_exp2f(acc[m][n][g]);
        rp[m][g] += ev;
        colpart[n] += ev;
      }

  // rows: reduce over 16 cols (lo16 lanes); lane lo16==m*4+g holds
  // row m*16 + q4*4 + g for its q4 group
  #pragma unroll
  for (int m = 0; m < 4; ++m)
    #pragma unroll
    for (int g = 0; g < 4; ++g) {
      float rs = rp[m][g];
      rs += __shfl_xor(rs, 1);
      rs += __shfl_xor(rs, 2);
      rs += __shfl_xor(rs, 4);
      rs += __shfl_xor(rs, 8);
      if (lo16 == m * 4 + g) {
        rowsum[w][m * 16 + q4 * 4 + g] = rs;
      }
    }

  // cols: sum the 4 q4 copies (different row groups) via xor 16,32
  #pragma unroll
  for (int n = 0; n < 2; ++n) {
    float cs = colpart[n];
    cs += __shfl_xor(cs, 16);
    cs += __shfl_xor(cs, 32);
    if (q4 == n) {
      atomicAdd(&out[NB + colblk * 128 + w * 32 + n * 16 + lo16], cs);
    }
  }

  __syncthreads();
  // rows: merge the 4 waves' copies (same 64 rows), one atomic per row
  if (tid < 64) {
    float s = rowsum[0][tid] + rowsum[1][tid] + rowsum[2][tid] + rowsum[3][tid];
    atomicAdd(&out[rowblk * 64 + tid], s);
  }
}

extern "C" void kernel_launch(void* const* d_in, const int* in_sizes, int n_in,
                              void* d_out, int out_size, void* d_ws, size_t ws_size,
                              hipStream_t stream) {
  const float* e = (const float*)d_in[0];
  const float* v = (const float*)d_in[1];
  float* out = (float*)d_out;
  unsigned short* ebf = (unsigned short*)d_ws;
  unsigned short* vbf = ebf + (size_t)NB * DK;
  hipLaunchKernelGGL(norm_kernel, dim3((2 * NB) / 4), dim3(256), 0, stream, e, v, ebf, vbf, out);
  hipLaunchKernelGGL(score_kernel, dim3(8192), dim3(256), 0, stream, ebf, vbf, out);
}

// Round 10
// 78.429 us; speedup vs baseline: 1.2668x; 1.1762x over previous
//
#include <hip/hip_runtime.h>
#include <hip/hip_bf16.h>
#include <stdint.h>

#define NB 8192
#define DK 256
// gamma * log2(e): epilogue uses native exp2
#define GSCALE 14.426950408889634f

typedef short short8 __attribute__((ext_vector_type(8)));
typedef float f32x4 __attribute__((ext_vector_type(4)));

__device__ __forceinline__ unsigned short f32_to_bf16(float f) {
  uint32_t u = __builtin_bit_cast(uint32_t, f);
  u += 0x7FFFu + ((u >> 16) & 1u);   // RNE
  return (unsigned short)(u >> 16);
}

// Normalize (gamma*log2e folded into e side) AND write in PACKED MFMA-fragment
// layout: fragment (row-panel p = r>>4, ks = k>>5) is a contiguous 1-KB chunk;
// lane l = (q4,lo16) owns bytes l*16..+16 = row (p*16+lo16... i.e. r&15),
// k-elems ks*32 + q4*8. packed_byte(r,k) =
//   (r>>4)*8192 + (k>>5)*1024 + ((k>>3)&3)*256 + (r&15)*16 + (k&7)*2.
// Lane l holds k = 4l..4l+3 -> one 8-B store at elem offset (l&1)*8.
// Blocks 0..15 also zero d_out (replaces hipMemsetAsync).
__global__ __launch_bounds__(256) void normpack_kernel(const float* __restrict__ e,
                                                       const float* __restrict__ v,
                                                       unsigned short* __restrict__ apk,
                                                       unsigned short* __restrict__ vpk,
                                                       float* __restrict__ out) {
  if (blockIdx.x < 16) {
    float4 z = {0.f, 0.f, 0.f, 0.f};
    reinterpret_cast<float4*>(out)[blockIdx.x * 256 + threadIdx.x] = z;
  }
  int wave = threadIdx.x >> 6;
  int lane = threadIdx.x & 63;
  int row = blockIdx.x * 4 + wave;          // 0..16383
  const float* src;
  unsigned short* dstbase;
  float mul;
  if (row < NB) {
    src = e + (size_t)row * DK; dstbase = apk; mul = GSCALE;
  } else {
    row -= NB;
    src = v + (size_t)row * DK; dstbase = vpk; mul = 1.0f;
  }
  float4 x = reinterpret_cast<const float4*>(src)[lane];   // k = 4*lane .. +3
  float ss = x.x * x.x + x.y * x.y + x.z * x.z + x.w * x.w;
  #pragma unroll
  for (int off = 32; off >= 1; off >>= 1) ss += __shfl_xor(ss, off);
  float s = mul / fmaxf(sqrtf(ss), 1e-8f);
  ushort4 o;
  o.x = f32_to_bf16(x.x * s);
  o.y = f32_to_bf16(x.y * s);
  o.z = f32_to_bf16(x.z * s);
  o.w = f32_to_bf16(x.w * s);
  size_t off = (size_t)(row >> 4) * 8192 + (size_t)(lane >> 3) * 1024 +
               ((lane >> 1) & 3) * 256 + (row & 15) * 16 + (lane & 1) * 8;
  *reinterpret_cast<ushort4*>((char*)dstbase + off) = o;
}

// R9 structure + PACKED operands. Wave = 64 rows x 32 cols, one K=256 pass,
// 16 waves/CU target. A panel = 32 contiguous 1-KB fragments -> linear
// global_load_lds (no swizzle); af ds_read = frag base + lane*16 ->
// conflict-free BY CONSTRUCTION (lanes 0-7 cover all 32 banks). B-frags =
// coalesced 1-KB loads through a 4-slot static register ring (lookahead 3).
// No barriers in the K-loop; TLP (4 waves/SIMD) hides latencies.
__global__ __launch_bounds__(256, 4) void score_kernel(const unsigned short* __restrict__ apk,
                                                       const unsigned short* __restrict__ vpk,
                                                       float* __restrict__ out) {
  __shared__ unsigned short As[16384];      // 32 KB packed A panel
  __shared__ float rowsum[4][64];           // 1 KB

  const int tid = threadIdx.x;
  const int w = tid >> 6;          // 0..3 (col quarter)
  const int lane = tid & 63;
  const int lo16 = lane & 15;
  const int q4 = lane >> 4;        // 0..3

  // 8192 blocks: xcd = id&7. Per XCD: 8 colblks; consecutive t walk rowblk
  // within one colblk -> B hot-set 64 KB, A panels stream through L2/L3.
  int id = blockIdx.x;
  int xcd = id & 7;
  int t = id >> 3;                      // 0..1023
  int colblk = (xcd << 3) | (t >> 7);   // 0..63  (128-col strip)
  int rowblk = t & 127;                 // 0..127 (64-row panel)

  // ---- Stage A panel: 32 KB, PURE LINEAR copy (packed layout) ----
  const char* aP = (const char*)apk + (size_t)rowblk * 32768;
  #pragma unroll
  for (int u = 0; u < 8; ++u) {
    int chunk = w * 8 + u;                     // 0..31 (1-KB fragments)
    const char* src = aP + chunk * 1024 + lane * 16;
    unsigned short* dst = &As[chunk * 512];
    __builtin_amdgcn_global_load_lds((const __attribute__((address_space(1))) uint32_t*)src,
                                     (__attribute__((address_space(3))) uint32_t*)dst, 16, 0, 0);
  }

  // ---- B prologue (after glds so vmcnt drain is cheap): coalesced 1-KB
  //      fragment loads. Col-panel cp = colblk*8 + w*2 + n. ----
  const char* bBase = (const char*)vpk + (size_t)(colblk * 8 + w * 2) * 8192;
  const char* p0 = bBase + lane * 16;           // n=0 frags: + ks*1024
  const char* p1 = bBase + 8192 + lane * 16;    // n=1 frags

  short8 S[4][2];
  #pragma unroll
  for (int s = 0; s < 3; ++s) {
    S[s][0] = *(const short8*)(p0 + s * 1024);
    S[s][1] = *(const short8*)(p1 + s * 1024);
  }

  asm volatile("s_waitcnt vmcnt(0)" ::: "memory");
  __builtin_amdgcn_s_barrier();
  asm volatile("" ::: "memory");

  f32x4 acc[4][2];
  #pragma unroll
  for (int m = 0; m < 4; ++m)
    #pragma unroll
    for (int n = 0; n < 2; ++n)
      #pragma unroll
      for (int q = 0; q < 4; ++q)
        acc[m][n][q] = 0.0f;

  // ---- K loop: 8 steps, no barriers, ring lookahead 3 ----
  #pragma unroll
  for (int ks = 0; ks < 8; ++ks) {
    if (ks < 5) {                                // prefetch slot ks+3 (static idx)
      S[(ks + 3) & 3][0] = *(const short8*)(p0 + (ks + 3) * 1024);
      S[(ks + 3) & 3][1] = *(const short8*)(p1 + (ks + 3) * 1024);
    }
    short8 af[4];
    #pragma unroll
    for (int m = 0; m < 4; ++m)
      af[m] = *(const short8*)((const char*)As + (m * 8 + ks) * 1024 + lane * 16);
    #pragma unroll
    for (int m = 0; m < 4; ++m) {
      acc[m][0] = __builtin_amdgcn_mfma_f32_16x16x32_bf16(af[m], S[ks & 3][0], acc[m][0], 0, 0, 0);
      acc[m][1] = __builtin_amdgcn_mfma_f32_16x16x32_bf16(af[m], S[ks & 3][1], acc[m][1], 0, 0, 0);
    }
  }

  // ---- epilogue: E = exp2(acc); rows -> LDS merge, cols -> atomics.
  // C/D layout: col = lane&15 (B side), row = (lane>>4)*4 + reg (A side).
  float colpart[2] = {0.f, 0.f};
  float rp[4][4];
  #pragma unroll
  for (int m = 0; m < 4; ++m)
    #pragma unroll
    for (int g = 0; g < 4; ++g)
      rp[m][g] = 0.0f;

  #pragma unroll
  for (int m = 0; m < 4; ++m)
    #pragma unroll
    for (int n = 0; n < 2; ++n)
      #pragma unroll
      for (int g = 0; g < 4; ++g) {
        float ev = __builtin_amdgcn_exp2f(acc[m][n][g]);
        rp[m][g] += ev;
        colpart[n] += ev;
      }

  #pragma unroll
  for (int m = 0; m < 4; ++m)
    #pragma unroll
    for (int g = 0; g < 4; ++g) {
      float rs = rp[m][g];
      rs += __shfl_xor(rs, 1);
      rs += __shfl_xor(rs, 2);
      rs += __shfl_xor(rs, 4);
      rs += __shfl_xor(rs, 8);
      if (lo16 == m * 4 + g) {
        rowsum[w][m * 16 + q4 * 4 + g] = rs;
      }
    }

  #pragma unroll
  for (int n = 0; n < 2; ++n) {
    float cs = colpart[n];
    cs += __shfl_xor(cs, 16);
    cs += __shfl_xor(cs, 32);
    if (q4 == n) {
      atomicAdd(&out[NB + colblk * 128 + w * 32 + n * 16 + lo16], cs);
    }
  }

  __syncthreads();
  if (tid < 64) {
    float s = rowsum[0][tid] + rowsum[1][tid] + rowsum[2][tid] + rowsum[3][tid];
    atomicAdd(&out[rowblk * 64 + tid], s);
  }
}

extern "C" void kernel_launch(void* const* d_in, const int* in_sizes, int n_in,
                              void* d_out, int out_size, void* d_ws, size_t ws_size,
                              hipStream_t stream) {
  const float* e = (const float*)d_in[0];
  const float* v = (const float*)d_in[1];
  float* out = (float*)d_out;
  unsigned short* apk = (unsigned short*)d_ws;                 // 4 MiB packed e
  unsigned short* vpk = apk + (size_t)NB * DK;                 // 4 MiB packed v
  hipLaunchKernelGGL(normpack_kernel, dim3((2 * NB) / 4), dim3(256), 0, stream, e, v, apk, vpk, out);
  hipLaunchKernelGGL(score_kernel, dim3(8192), dim3(256), 0, stream, apk, vpk, out);
}